// Round 2
// baseline (336.695 us; speedup 1.0000x reference)
//
#include <hip/hip_runtime.h>

#define IC 3
#define OCH 16
#define IDD 16
#define IHH 32
#define IWW 32
#define ODD 31
#define OHH 63
#define OWW 63
#define NB 32

// Fused ConvTranspose3d(3->16,k3,s2,p1) + channel-LSE + x*sigmoid(x+3)/6 - bias, clip [-1,1].
// Parity decomposition: each thread computes a 2(oh) x 2(ow) patch.
// Weights staged in LDS once per block (uniform reads broadcast -> conflict-free).
// Each block processes an od-PAIR (2t even: kd=1 @ plane t; 2t+1 odd: kd=0 @ plane t+1,
// kd=2 @ plane t) so the staging prologue amortizes over 2 planes, plane-t x loads are
// L1-hot on the second pass, and the grid (2048 blocks) fits one full-residency round.
__global__ __launch_bounds__(256) void convt_lse_kernel(
    const float* __restrict__ x, const float* __restrict__ w,
    const float* __restrict__ bias, float* __restrict__ out)
{
    // LDS weights: [ic][kd][kh][kw][oc], oc contiguous for ds_read_b128
    __shared__ float wl[IC * 27 * OCH];
    for (int idx = threadIdx.x; idx < IC * 27 * OCH; idx += 256) {
        int ic   = idx / (27 * OCH);
        int rem  = idx - ic * (27 * OCH);
        int kpos = rem >> 4;   // kd*9 + kh*3 + kw
        int oc   = rem & 15;
        wl[idx] = w[(ic * OCH + oc) * 27 + kpos];
    }
    __syncthreads();

    const int j  = threadIdx.x & 31;                       // ow pair index: ow = 2j, 2j+1
    const int i  = (threadIdx.x >> 5) + (blockIdx.x << 3); // oh pair index: oh = 2i, 2i+1
    const int t  = blockIdx.y;                             // od pair: od = 2t, 2t+1
    const int b  = blockIdx.z;                             // [0,32)

    const int ih0 = i;
    const int ih1 = min(i + 1, IHH - 1);   // clamped: only feeds non-stored rows at i=31
    const int iw0 = j;
    const int iw1 = min(j + 1, IWW - 1);   // clamped: only feeds non-stored cols at j=31

    const float bv = bias[0];

    // acc[p][oc]: p0=(even,even) p1=(even,odd) p2=(odd,even) p3=(odd,odd)
    float acc[4][OCH];

    auto zero_acc = [&]() {
        #pragma unroll
        for (int p = 0; p < 4; ++p)
            #pragma unroll
            for (int oc = 0; oc < OCH; ++oc) acc[p][oc] = 0.0f;
    };

    auto do_tap = [&](int kd, int id) {
        #pragma unroll
        for (int ic = 0; ic < IC; ++ic) {
            const float* __restrict__ xp = x + (((b * IC + ic) * IDD + id) << 10);
            const float x00 = xp[ih0 * IWW + iw0];
            const float x01 = xp[ih0 * IWW + iw1];
            const float x10 = xp[ih1 * IWW + iw0];
            const float x11 = xp[ih1 * IWW + iw1];
            const float* __restrict__ wp = &wl[(ic * 3 + kd) * 9 * OCH];
            #pragma unroll
            for (int oc = 0; oc < OCH; ++oc) {
                // (even oh, even ow): kh=1,kw=1
                acc[0][oc] = fmaf(x00, wp[4 * OCH + oc], acc[0][oc]);
                // (even, odd): kh=1, kw=0 (x[.][j+1]) + kw=2 (x[.][j])
                acc[1][oc] = fmaf(x01, wp[3 * OCH + oc],
                             fmaf(x00, wp[5 * OCH + oc], acc[1][oc]));
                // (odd, even): kw=1, kh=0 (x[i+1][.]) + kh=2 (x[i][.])
                acc[2][oc] = fmaf(x10, wp[1 * OCH + oc],
                             fmaf(x00, wp[7 * OCH + oc], acc[2][oc]));
                // (odd, odd): (0,0)x11 (0,2)x10 (2,0)x01 (2,2)x00
                acc[3][oc] = fmaf(x11, wp[0 * OCH + oc],
                             fmaf(x10, wp[2 * OCH + oc],
                             fmaf(x01, wp[6 * OCH + oc],
                             fmaf(x00, wp[8 * OCH + oc], acc[3][oc]))));
            }
        }
    };

    auto finish = [&](int od) {
        const int oh0   = 2 * i;
        const int ow0   = 2 * j;
        const int obase = (b * ODD + od) * OHH;
        #pragma unroll
        for (int p = 0; p < 4; ++p) {
            const int oh = oh0 + (p >> 1);
            const int ow = ow0 + (p & 1);
            if (oh < OHH && ow < OWW) {
                // tree max (breaks the 15-deep serial fmax chain)
                float mt[8];
                #pragma unroll
                for (int k = 0; k < 8; ++k) mt[k] = fmaxf(acc[p][k], acc[p][k + 8]);
                #pragma unroll
                for (int k = 0; k < 4; ++k) mt[k] = fmaxf(mt[k], mt[k + 4]);
                const float m = fmaxf(fmaxf(mt[0], mt[1]), fmaxf(mt[2], mt[3]));
                // tree sum of exps
                float e[16];
                #pragma unroll
                for (int oc = 0; oc < OCH; ++oc) e[oc] = __expf(acc[p][oc] - m);
                #pragma unroll
                for (int k = 0; k < 8; ++k) e[k] += e[k + 8];
                #pragma unroll
                for (int k = 0; k < 4; ++k) e[k] += e[k + 4];
                const float s  = (e[0] + e[1]) + (e[2] + e[3]);
                const float v  = m + __logf(s);
                // hardswish-ish: v * sigmoid(v+3) / 6, fast rcp (1ulp, << absmax tol)
                const float hs = v * __builtin_amdgcn_rcpf(6.0f * (1.0f + __expf(-(v + 3.0f))));
                const float r  = fminf(1.0f, fmaxf(-1.0f, hs - bv));
                out[(obase + oh) * OWW + ow] = r;
            }
        }
    };

    // even od = 2t: single center tap kd=1, id=t
    zero_acc();
    do_tap(1, t);
    finish(2 * t);

    // odd od = 2t+1 (exists for t<15): kd=0 @ id=t+1, kd=2 @ id=t
    if (t < 15) {
        zero_acc();
        do_tap(0, t + 1);
        do_tap(2, t);
        finish(2 * t + 1);
    }
}

extern "C" void kernel_launch(void* const* d_in, const int* in_sizes, int n_in,
                              void* d_out, int out_size, void* d_ws, size_t ws_size,
                              hipStream_t stream) {
    const float* x    = (const float*)d_in[0];
    const float* w    = (const float*)d_in[1];
    const float* bias = (const float*)d_in[2];
    float* out        = (float*)d_out;

    dim3 grid(4, 16, NB);   // 4 i-chunks (8 i-values each) x od-pairs x batch
    dim3 block(256);
    convt_lse_kernel<<<grid, block, 0, stream>>>(x, w, bias, out);
}

// Round 3
// 115.649 us; speedup vs baseline: 2.9113x; 2.9113x over previous
//
#include <hip/hip_runtime.h>

#define IC 3
#define OCH 16
#define IDD 16
#define IHH 32
#define IWW 32
#define ODD 31
#define OHH 63
#define OWW 63
#define NB 32

typedef float v4 __attribute__((ext_vector_type(4)));

// Fused ConvTranspose3d(3->16,k3,s2,p1) + channel-LSE + x*sigmoid(x+3)/6 - bias, clip [-1,1].
// Parity decomposition; each thread computes TWO ow-pairs x one oh-pair = 8 pixels at one od.
// oc is processed in 2 chunks of 8 (acc[8][8] = 64 regs, the proven-safe size) with a plain
// running sum-of-exp per pixel (no max subtraction: |conv| <= ~4 so exp can't overflow fp32).
// Rationale: round-0 had 1 FMA per LDS weight float (LDS pipe 4-SIMD oversubscribed -> 50%
// stall); 2 ow-pairs make each weight register feed 2 FMAs, halving LDS broadcast traffic.
__global__ __launch_bounds__(256) void convt_lse_kernel(
    const float* __restrict__ x, const float* __restrict__ w,
    const float* __restrict__ bias, float* __restrict__ out)
{
    // LDS weights: [ic][kd][kh*3+kw][oc], oc contiguous for ds_read_b128
    __shared__ __align__(16) float wl[IC * 27 * OCH];
    for (int idx = threadIdx.x; idx < IC * 27 * OCH; idx += 256) {
        int ic   = idx / (27 * OCH);
        int rem  = idx - ic * (27 * OCH);
        int kpos = rem >> 4;   // kd*9 + kh*3 + kw
        int oc   = rem & 15;
        wl[idx] = w[(ic * OCH + oc) * 27 + kpos];
    }
    __syncthreads();

    const int jj = threadIdx.x & 15;                        // ow base = 4*jj (2 ow-pairs)
    const int i  = (threadIdx.x >> 4) + (blockIdx.x << 4);  // oh pair: oh = 2i, 2i+1
    const int od = blockIdx.y;                              // [0,31)
    const int b  = blockIdx.z;                              // [0,32)

    const int r0 = i * IWW;
    const int r1 = min(i + 1, IHH - 1) * IWW;  // clamp: feeds only non-stored oh=63
    const int c0 = 2 * jj;
    const int c1 = 2 * jj + 1;
    const int c2 = min(2 * jj + 2, IWW - 1);   // clamp: feeds only non-stored ow=63

    float ss[8];
    #pragma unroll
    for (int px = 0; px < 8; ++px) ss[px] = 0.0f;

    #pragma unroll 1                 // keep ONE acc copy live (round-2 spill lesson)
    for (int chunk = 0; chunk < 2; ++chunk) {
        // acc[px][c]: px = q*4+p, q = ow-pair (A at 4jj, B at 4jj+2),
        // p: 0=(even oh,even ow) 1=(even,odd) 2=(odd,even) 3=(odd,odd)
        float acc[8][8];
        #pragma unroll
        for (int px = 0; px < 8; ++px)
            #pragma unroll
            for (int c = 0; c < 8; ++c) acc[px][c] = 0.0f;

        auto tap = [&](int kd, int id) {
            #pragma unroll
            for (int ic = 0; ic < IC; ++ic) {
                const float* __restrict__ xp = x + (((b * IC + ic) * IDD + id) << 10);
                const float xa0 = xp[r0 + c0], xa1 = xp[r0 + c1], xa2 = xp[r0 + c2];
                const float xb0 = xp[r1 + c0], xb1 = xp[r1 + c1], xb2 = xp[r1 + c2];
                const v4* __restrict__ wv = (const v4*)(wl + (ic * 3 + kd) * 9 * OCH);
                #pragma unroll
                for (int q4 = 0; q4 < 2; ++q4) {
                    const int o = chunk * 2 + q4;   // oc quad select within [pos][oc16]
                    const v4 w0 = wv[o],      w1 = wv[4 + o],  w2 = wv[8 + o];
                    const v4 w3 = wv[12 + o], w4 = wv[16 + o], w5 = wv[20 + o];
                    const v4 w6 = wv[24 + o], w7 = wv[28 + o], w8 = wv[32 + o];
                    #pragma unroll
                    for (int oc = 0; oc < 4; ++oc) {
                        const int c = q4 * 4 + oc;
                        // pair A: iw0=c0, iw1=c1
                        acc[0][c] = fmaf(xa0, w4[oc], acc[0][c]);
                        acc[1][c] = fmaf(xa1, w3[oc], fmaf(xa0, w5[oc], acc[1][c]));
                        acc[2][c] = fmaf(xb0, w1[oc], fmaf(xa0, w7[oc], acc[2][c]));
                        acc[3][c] = fmaf(xb1, w0[oc],
                                    fmaf(xb0, w2[oc],
                                    fmaf(xa1, w6[oc],
                                    fmaf(xa0, w8[oc], acc[3][c]))));
                        // pair B: iw0=c1, iw1=c2
                        acc[4][c] = fmaf(xa1, w4[oc], acc[4][c]);
                        acc[5][c] = fmaf(xa2, w3[oc], fmaf(xa1, w5[oc], acc[5][c]));
                        acc[6][c] = fmaf(xb1, w1[oc], fmaf(xa1, w7[oc], acc[6][c]));
                        acc[7][c] = fmaf(xb2, w0[oc],
                                    fmaf(xb1, w2[oc],
                                    fmaf(xa2, w6[oc],
                                    fmaf(xa1, w8[oc], acc[7][c]))));
                    }
                }
            }
        };

        if (od & 1) {           // odd od: kd=0 @ id=(od+1)/2, kd=2 @ id=(od-1)/2
            tap(0, (od + 1) >> 1);
            tap(2, (od - 1) >> 1);
        } else {                // even od: kd=1 @ id=od/2
            tap(1, od >> 1);
        }

        // chunk's sum-of-exp into running ss (no max-sub: |acc| <= ~4 << 88)
        #pragma unroll
        for (int px = 0; px < 8; ++px) {
            float e[8];
            #pragma unroll
            for (int c = 0; c < 8; ++c) e[c] = __expf(acc[px][c]);
            #pragma unroll
            for (int c = 0; c < 4; ++c) e[c] += e[c + 4];
            ss[px] += (e[0] + e[1]) + (e[2] + e[3]);
        }
    }

    const float bv  = bias[0];
    const int oh0   = 2 * i;
    const int obase = (b * ODD + od) * OHH;

    #pragma unroll
    for (int q = 0; q < 2; ++q)
        #pragma unroll
        for (int p = 0; p < 4; ++p) {
            const int px = q * 4 + p;
            const int oh = oh0 + (p >> 1);
            const int ow = 4 * jj + 2 * q + (p & 1);
            if (oh < OHH && ow < OWW) {
                const float v  = __logf(ss[px]);
                const float hs = v * __builtin_amdgcn_rcpf(6.0f * (1.0f + __expf(-(v + 3.0f))));
                const float r  = fminf(1.0f, fmaxf(-1.0f, hs - bv));
                out[(obase + oh) * OWW + ow] = r;
            }
        }
}

extern "C" void kernel_launch(void* const* d_in, const int* in_sizes, int n_in,
                              void* d_out, int out_size, void* d_ws, size_t ws_size,
                              hipStream_t stream) {
    const float* x    = (const float*)d_in[0];
    const float* w    = (const float*)d_in[1];
    const float* bias = (const float*)d_in[2];
    float* out        = (float*)d_out;

    dim3 grid(2, ODD, NB);   // 2 i-chunks (16 i-values each) x od x batch
    dim3 block(256);
    convt_lse_kernel<<<grid, block, 0, stream>>>(x, w, bias, out);
}

// Round 4
// 94.222 us; speedup vs baseline: 3.5734x; 1.2274x over previous
//
#include <hip/hip_runtime.h>

#define IC 3
#define OCH 16
#define IDD 16
#define IHH 32
#define IWW 32
#define ODD 31
#define OHH 63
#define OWW 63
#define NB 32

typedef float f2 __attribute__((ext_vector_type(2)));

#define LOG2E 1.44269504088896340736f
#define LN2   0.69314718055994530942f

static __device__ __forceinline__ f2 fma2(f2 a, f2 b, f2 c) {
    return __builtin_elementwise_fma(a, b, c);   // -> v_pk_fma_f32
}

// Fused ConvTranspose3d(3->16,k3,s2,p1) + channel-LSE + x*sigmoid(x+3)/6 - bias, clip [-1,1].
// Round-0 structure (2x2 patch/thread, 4 waves/block, VGPR-lean) + three deltas:
//  1) oc paired into float2 -> v_pk_fma_f32 halves conv VALU inst count (641 -> ~320/thread)
//  2) x prefetched to registers BEFORE weight staging + barrier (global latency hides there)
//  3) weights pre-scaled by log2(e) in LDS -> sum-of-exp uses raw v_exp (exp2), no per-element
//     range conversion; no max-subtraction (|conv| <= ~6, validated round 3); fast log2/rcp tail.
__global__ __launch_bounds__(256) void convt_lse_kernel(
    const float* __restrict__ x, const float* __restrict__ w,
    const float* __restrict__ bias, float* __restrict__ out)
{
    __shared__ __align__(16) float wl[IC * 27 * OCH];

    const int j  = threadIdx.x & 31;                       // ow pair: ow = 2j, 2j+1
    const int i  = (threadIdx.x >> 5) + (blockIdx.x << 3); // oh pair: oh = 2i, 2i+1
    const int od = blockIdx.y;
    const int b  = blockIdx.z;

    const int ih0 = i;
    const int ih1 = min(i + 1, IHH - 1);   // clamp: feeds only non-stored oh=63
    const int iw0 = j;
    const int iw1 = min(j + 1, IWW - 1);   // clamp: feeds only non-stored ow=63

    const bool odd = (od & 1) != 0;
    const int id0 = odd ? ((od + 1) >> 1) : (od >> 1);
    const int id1 = (od - 1) >> 1;         // used only when odd

    // ---- x prefetch: issue global loads before staging so latency hides under it
    float xr[2][IC][4];    // [tap][ic][{00,01,10,11}] - all indices compile-time below
    #pragma unroll
    for (int ic = 0; ic < IC; ++ic) {
        const float* __restrict__ xp = x + (((b * IC + ic) * IDD + id0) << 10);
        xr[0][ic][0] = xp[ih0 * IWW + iw0];
        xr[0][ic][1] = xp[ih0 * IWW + iw1];
        xr[0][ic][2] = xp[ih1 * IWW + iw0];
        xr[0][ic][3] = xp[ih1 * IWW + iw1];
    }
    if (odd) {
        #pragma unroll
        for (int ic = 0; ic < IC; ++ic) {
            const float* __restrict__ xp = x + (((b * IC + ic) * IDD + id1) << 10);
            xr[1][ic][0] = xp[ih0 * IWW + iw0];
            xr[1][ic][1] = xp[ih0 * IWW + iw1];
            xr[1][ic][2] = xp[ih1 * IWW + iw0];
            xr[1][ic][3] = xp[ih1 * IWW + iw1];
        }
    }
    const float bv = bias[0];

    // ---- stage weights (scaled to exp2 domain): [ic][kd][kh*3+kw][oc]
    for (int idx = threadIdx.x; idx < IC * 27 * OCH; idx += 256) {
        int ic   = idx / (27 * OCH);
        int rem  = idx - ic * (27 * OCH);
        int kpos = rem >> 4;   // kd*9 + kh*3 + kw
        int oc   = rem & 15;
        wl[idx] = w[(ic * OCH + oc) * 27 + kpos] * LOG2E;
    }
    __syncthreads();

    // acc[p][cp]: p 0=(ee) 1=(eo) 2=(oe) 3=(oo); cp = oc pair (2 channels)
    f2 acc[4][8];

#define EMIT(first, x00, x01, x10, x11, wp2)                                          \
    {                                                                                 \
        _Pragma("unroll")                                                             \
        for (int cp = 0; cp < 8; ++cp) {                                              \
            const f2 w0 = wp2[0 * 8 + cp], w1 = wp2[1 * 8 + cp], w2 = wp2[2 * 8 + cp],\
                     w3 = wp2[3 * 8 + cp], w4 = wp2[4 * 8 + cp], w5 = wp2[5 * 8 + cp],\
                     w6 = wp2[6 * 8 + cp], w7 = wp2[7 * 8 + cp], w8 = wp2[8 * 8 + cp];\
            if (first) {                                                              \
                acc[3][cp] = x11 * w0;                                                \
                acc[2][cp] = x10 * w1;                                                \
                acc[1][cp] = x01 * w3;                                                \
                acc[0][cp] = x00 * w4;                                                \
            } else {                                                                  \
                acc[3][cp] = fma2(x11, w0, acc[3][cp]);                               \
                acc[2][cp] = fma2(x10, w1, acc[2][cp]);                               \
                acc[1][cp] = fma2(x01, w3, acc[1][cp]);                               \
                acc[0][cp] = fma2(x00, w4, acc[0][cp]);                               \
            }                                                                         \
            acc[3][cp] = fma2(x10, w2, acc[3][cp]);                                   \
            acc[1][cp] = fma2(x00, w5, acc[1][cp]);                                   \
            acc[3][cp] = fma2(x01, w6, acc[3][cp]);                                   \
            acc[2][cp] = fma2(x00, w7, acc[2][cp]);                                   \
            acc[3][cp] = fma2(x00, w8, acc[3][cp]);                                   \
        }                                                                             \
    }

#define DO_TAP(kd, tpi, first)                                                        \
    {                                                                                 \
        _Pragma("unroll")                                                             \
        for (int ic = 0; ic < IC; ++ic) {                                             \
            const f2 x00 = {xr[tpi][ic][0], xr[tpi][ic][0]};                          \
            const f2 x01 = {xr[tpi][ic][1], xr[tpi][ic][1]};                          \
            const f2 x10 = {xr[tpi][ic][2], xr[tpi][ic][2]};                          \
            const f2 x11 = {xr[tpi][ic][3], xr[tpi][ic][3]};                          \
            const f2* __restrict__ wp2 = (const f2*)(wl + (ic * 3 + (kd)) * 9 * OCH); \
            EMIT((first) && ic == 0, x00, x01, x10, x11, wp2)                         \
        }                                                                             \
    }

    if (odd) {          // odd od: kd=0 @ id0=(od+1)/2, kd=2 @ id1=(od-1)/2
        DO_TAP(0, 0, true)
        DO_TAP(2, 1, false)
    } else {            // even od: kd=1 @ id0=od/2
        DO_TAP(1, 0, true)
    }

    const int oh0   = 2 * i;
    const int ow0   = 2 * j;
    const int obase = (b * ODD + od) * OHH;

    #pragma unroll
    for (int p = 0; p < 4; ++p) {
        const int oh = oh0 + (p >> 1);
        const int ow = ow0 + (p & 1);
        if (oh < OHH && ow < OWW) {
            // acc is log2-domain: sum of exp2, two packed partial sums
            f2 sa = {0.0f, 0.0f}, sb = {0.0f, 0.0f};
            #pragma unroll
            for (int cp = 0; cp < 8; cp += 2) {
                f2 ea, eb;
                ea.x = __builtin_amdgcn_exp2f(acc[p][cp].x);
                ea.y = __builtin_amdgcn_exp2f(acc[p][cp].y);
                eb.x = __builtin_amdgcn_exp2f(acc[p][cp + 1].x);
                eb.y = __builtin_amdgcn_exp2f(acc[p][cp + 1].y);
                sa += ea;                       // v_pk_add_f32
                sb += eb;
            }
            const f2 st   = sa + sb;
            const float S = st.x + st.y;
            const float v = LN2 * __builtin_amdgcn_logf(S);          // ln(S)
            // hardswish-ish: v / (6*(1+exp(-(v+3)))); exp via exp2(fma)
            const float t   = __builtin_amdgcn_exp2f(fmaf(-LOG2E, v, -3.0f * LOG2E));
            const float den = fmaf(6.0f, t, 6.0f);
            const float hs  = v * __builtin_amdgcn_rcpf(den);
            const float r   = fminf(1.0f, fmaxf(-1.0f, hs - bv));
            out[(obase + oh) * OWW + ow] = r;
        }
    }
}

extern "C" void kernel_launch(void* const* d_in, const int* in_sizes, int n_in,
                              void* d_out, int out_size, void* d_ws, size_t ws_size,
                              hipStream_t stream) {
    const float* x    = (const float*)d_in[0];
    const float* w    = (const float*)d_in[1];
    const float* bias = (const float*)d_in[2];
    float* out        = (float*)d_out;

    dim3 grid(4, ODD, NB);   // 4 i-chunks (8 i-values each) x od x batch
    dim3 block(256);
    convt_lse_kernel<<<grid, block, 0, stream>>>(x, w, bias, out);
}